// Round 1
// baseline (636.545 us; speedup 1.0000x reference)
//
#include <hip/hip_runtime.h>
#include <hip/hip_bf16.h>
#include <stdint.h>

#define B_ 32
#define S_ 2048
#define H_ 1024

typedef __attribute__((ext_vector_type(8))) short short8;
typedef __attribute__((ext_vector_type(4))) float floatx4;

__device__ inline unsigned short f32_bf16(float f) {
    union { float f; unsigned u; } v; v.f = f;
    unsigned u = v.u;
    u += 0x7fff + ((u >> 16) & 1);   // round-to-nearest-even
    return (unsigned short)(u >> 16);
}

__device__ inline float tanh_fast(float x) {
    float e = __expf(2.0f * x);
    return 1.0f - 2.0f / (e + 1.0f);
}

// ---------------- zero scratch (scores in ws, context region of d_out) -------
__global__ void k_zero2(float* a, int na, float* b, int nb) {
    int i = blockIdx.x * 256 + threadIdx.x;
    if (i < na) a[i] = 0.0f;
    else if (i - na < nb) b[i - na] = 0.0f;
}

// ---------------- Ua_w fp32 -> bf16 ------------------------------------------
__global__ void k_cvt_ua(const float* __restrict__ ua, unsigned short* __restrict__ out) {
    int i = (blockIdx.x * 256 + threadIdx.x) * 4;
    float4 f = *(const float4*)(ua + i);
    unsigned lo = f32_bf16(f.x) | ((unsigned)f32_bf16(f.y) << 16);
    unsigned hi = f32_bf16(f.z) | ((unsigned)f32_bf16(f.w) << 16);
    *(uint2*)(out + i) = make_uint2(lo, hi);
}

// ---------------- qsum[b,g] = query[b]·Wa_w[g] + Wa_b[g] + Ua_b[g] -----------
__global__ void k_qproj(const float* __restrict__ query, const float* __restrict__ Wa_w,
                        const float* __restrict__ Wa_b, const float* __restrict__ Ua_b,
                        float* __restrict__ qsum) {
    int b = blockIdx.x >> 2;
    int g = ((blockIdx.x & 3) << 8) + threadIdx.x;
    const float4* q4 = (const float4*)(query + (size_t)b * H_);
    const float4* w4 = (const float4*)(Wa_w + (size_t)g * H_);
    float acc = 0.0f;
#pragma unroll 4
    for (int h = 0; h < H_ / 4; ++h) {
        float4 a = q4[h], w = w4[h];
        acc += a.x * w.x + a.y * w.y + a.z * w.z + a.w * w.w;
    }
    qsum[b * H_ + g] = acc + Wa_b[g] + Ua_b[g];
}

// ---------------- fused GEMM + tanh + Va reduction ---------------------------
// C[ms,g] = sum_h keys[ms,h] * Ua[g,h]  (NT GEMM, bf16 MFMA 16x16x32)
// scores[ms] += sum_g Va[g] * tanh(qsum[b,g] + C[ms,g])   (atomic partial)
#define BM 128
#define BN 128
#define BK 32
#define LDA 48   // LDS row stride in bf16 elems (96 B: 16B-aligned, odd-ish bank shift)

__global__ __launch_bounds__(256, 2) void k_scores(
    const float* __restrict__ keys, const unsigned short* __restrict__ uab,
    const float* __restrict__ qsum, const float* __restrict__ va,
    float* __restrict__ scores)
{
    __shared__ unsigned short Al[BM * LDA];
    __shared__ unsigned short Bl[BN * LDA];

    int bx = blockIdx.x;
    // XCD swizzle: 8 n-chunks of one tile_m stay on one XCD (A-tile L2 reuse)
    int x  = bx & 7;
    int i  = bx >> 3;
    int tile_m = x * 64 + (i >> 3);
    int nc     = i & 7;
    int m_base = tile_m * BM;          // global row = b*S + s
    int b      = m_base >> 11;
    int g0     = nc * BN;

    int tid = threadIdx.x;
    int wid = tid >> 6, lane = tid & 63;
    int wm = wid >> 1, wn = wid & 1;
    int q = lane >> 4, cn = lane & 15;

    const float*          Aptr = keys + (size_t)m_base * H_;
    const unsigned short* Bptr = uab  + (size_t)g0 * H_;

    int ar = tid >> 3;   // 0..31 (A row, 4 sweeps of 32)
    int ac = tid & 7;    // float4 col within BK
    int br = tid >> 2;   // 0..63 (B row, 2 sweeps of 64)
    int bc = tid & 3;    // 8-elem col within BK

    floatx4 acc[4][4];
#pragma unroll
    for (int ii = 0; ii < 4; ++ii)
#pragma unroll
        for (int jj = 0; jj < 4; ++jj)
            acc[ii][jj] = (floatx4)(0.0f);

    float4 a0, a1, a2, a3;
    uint4  bv0, bv1;
    // preload chunk 0
    {
        int k0 = 0;
        a0 = *(const float4*)(Aptr + (size_t)(ar      ) * H_ + k0 + ac * 4);
        a1 = *(const float4*)(Aptr + (size_t)(ar + 32 ) * H_ + k0 + ac * 4);
        a2 = *(const float4*)(Aptr + (size_t)(ar + 64 ) * H_ + k0 + ac * 4);
        a3 = *(const float4*)(Aptr + (size_t)(ar + 96 ) * H_ + k0 + ac * 4);
        bv0 = *(const uint4*)(Bptr + (size_t)(br      ) * H_ + k0 + bc * 8);
        bv1 = *(const uint4*)(Bptr + (size_t)(br + 64 ) * H_ + k0 + bc * 8);
    }

    for (int kc = 0; kc < H_ / BK; ++kc) {
        __syncthreads();   // previous iteration's frag reads complete
        // convert + write A (fp32 -> bf16), 8 B per row-slot
        {
            unsigned short* p;
            unsigned lo, hi;
            p = Al + (ar      ) * LDA + ac * 4;
            lo = f32_bf16(a0.x) | ((unsigned)f32_bf16(a0.y) << 16);
            hi = f32_bf16(a0.z) | ((unsigned)f32_bf16(a0.w) << 16);
            *(uint2*)p = make_uint2(lo, hi);
            p = Al + (ar + 32 ) * LDA + ac * 4;
            lo = f32_bf16(a1.x) | ((unsigned)f32_bf16(a1.y) << 16);
            hi = f32_bf16(a1.z) | ((unsigned)f32_bf16(a1.w) << 16);
            *(uint2*)p = make_uint2(lo, hi);
            p = Al + (ar + 64 ) * LDA + ac * 4;
            lo = f32_bf16(a2.x) | ((unsigned)f32_bf16(a2.y) << 16);
            hi = f32_bf16(a2.z) | ((unsigned)f32_bf16(a2.w) << 16);
            *(uint2*)p = make_uint2(lo, hi);
            p = Al + (ar + 96 ) * LDA + ac * 4;
            lo = f32_bf16(a3.x) | ((unsigned)f32_bf16(a3.y) << 16);
            hi = f32_bf16(a3.z) | ((unsigned)f32_bf16(a3.w) << 16);
            *(uint2*)p = make_uint2(lo, hi);
            *(uint4*)(Bl + (br      ) * LDA + bc * 8) = bv0;
            *(uint4*)(Bl + (br + 64 ) * LDA + bc * 8) = bv1;
        }
        // issue next chunk's global loads (latency hidden behind MFMA)
        if (kc + 1 < H_ / BK) {
            int k0 = (kc + 1) * BK;
            a0 = *(const float4*)(Aptr + (size_t)(ar      ) * H_ + k0 + ac * 4);
            a1 = *(const float4*)(Aptr + (size_t)(ar + 32 ) * H_ + k0 + ac * 4);
            a2 = *(const float4*)(Aptr + (size_t)(ar + 64 ) * H_ + k0 + ac * 4);
            a3 = *(const float4*)(Aptr + (size_t)(ar + 96 ) * H_ + k0 + ac * 4);
            bv0 = *(const uint4*)(Bptr + (size_t)(br      ) * H_ + k0 + bc * 8);
            bv1 = *(const uint4*)(Bptr + (size_t)(br + 64 ) * H_ + k0 + bc * 8);
        }
        __syncthreads();   // LDS tile visible
        short8 af[4], bf[4];
#pragma unroll
        for (int ii = 0; ii < 4; ++ii)
            af[ii] = *(const short8*)(Al + (wm * 64 + ii * 16 + cn) * LDA + q * 8);
#pragma unroll
        for (int jj = 0; jj < 4; ++jj)
            bf[jj] = *(const short8*)(Bl + (wn * 64 + jj * 16 + cn) * LDA + q * 8);
#pragma unroll
        for (int ii = 0; ii < 4; ++ii)
#pragma unroll
            for (int jj = 0; jj < 4; ++jj)
                acc[ii][jj] = __builtin_amdgcn_mfma_f32_16x16x32_bf16(
                    af[ii], bf[jj], acc[ii][jj], 0, 0, 0);
    }

    // epilogue: scores partial = sum_g Va[g] * tanh(qsum[b,g] + C)
    float qs[4], vw[4];
#pragma unroll
    for (int jj = 0; jj < 4; ++jj) {
        int g = g0 + wn * 64 + jj * 16 + cn;
        qs[jj] = qsum[b * H_ + g];
        vw[jj] = va[g];
    }
#pragma unroll
    for (int ii = 0; ii < 4; ++ii) {
        float rs[4] = {0.f, 0.f, 0.f, 0.f};
#pragma unroll
        for (int jj = 0; jj < 4; ++jj) {
#pragma unroll
            for (int r = 0; r < 4; ++r)
                rs[r] += vw[jj] * tanh_fast(qs[jj] + acc[ii][jj][r]);
        }
#pragma unroll
        for (int r = 0; r < 4; ++r) {
            for (int mm = 1; mm < 16; mm <<= 1)
                rs[r] += __shfl_xor(rs[r], mm);
        }
        if (cn == 0) {
            int msrow = m_base + wm * 64 + ii * 16 + q * 4;   // +r below
            float* sp = scores + b * S_ + (msrow & (S_ - 1));
            atomicAdd(sp + 0, rs[0]);
            atomicAdd(sp + 1, rs[1]);
            atomicAdd(sp + 2, rs[2]);
            atomicAdd(sp + 3, rs[3]);
        }
    }
}

// ---------------- softmax over S per batch -----------------------------------
__global__ void k_softmax(const float* __restrict__ scores, float* __restrict__ weights) {
    int b = blockIdx.x;
    int t = threadIdx.x;
    __shared__ float red[4];
    float v[8];
    float mx = -1e30f;
#pragma unroll
    for (int k = 0; k < 8; ++k) { v[k] = scores[b * S_ + t + k * 256]; mx = fmaxf(mx, v[k]); }
    for (int mm = 1; mm < 64; mm <<= 1) mx = fmaxf(mx, __shfl_xor(mx, mm));
    if ((t & 63) == 0) red[t >> 6] = mx;
    __syncthreads();
    mx = fmaxf(fmaxf(red[0], red[1]), fmaxf(red[2], red[3]));
    float sum = 0.0f;
#pragma unroll
    for (int k = 0; k < 8; ++k) { v[k] = __expf(v[k] - mx); sum += v[k]; }
    for (int mm = 1; mm < 64; mm <<= 1) sum += __shfl_xor(sum, mm);
    __syncthreads();
    if ((t & 63) == 0) red[t >> 6] = sum;
    __syncthreads();
    sum = red[0] + red[1] + red[2] + red[3];
    float inv = 1.0f / sum;
#pragma unroll
    for (int k = 0; k < 8; ++k) weights[b * S_ + t + k * 256] = v[k] * inv;
}

// ---------------- context[b,h] = sum_s w[b,s] * keys[b,s,h] ------------------
__global__ void k_context(const float* __restrict__ keys, const float* __restrict__ weights,
                          float* __restrict__ ctx) {
    int blk = blockIdx.x;        // 1024 blocks: b (32) x s-chunk (32 of 64)
    int b  = blk >> 5;
    int sc = blk & 31;
    int t  = threadIdx.x;
    const float4* kp = (const float4*)(keys + (size_t)(b * S_ + sc * 64) * H_);
    const float*  wp = weights + b * S_ + sc * 64;
    float4 acc = {0.f, 0.f, 0.f, 0.f};
#pragma unroll 4
    for (int s = 0; s < 64; ++s) {
        float w = wp[s];
        float4 k4 = kp[(size_t)s * (H_ / 4) + t];
        acc.x += w * k4.x; acc.y += w * k4.y; acc.z += w * k4.z; acc.w += w * k4.w;
    }
    float* cp = ctx + b * H_ + t * 4;
    atomicAdd(cp + 0, acc.x); atomicAdd(cp + 1, acc.y);
    atomicAdd(cp + 2, acc.z); atomicAdd(cp + 3, acc.w);
}

// -----------------------------------------------------------------------------
extern "C" void kernel_launch(void* const* d_in, const int* in_sizes, int n_in,
                              void* d_out, int out_size, void* d_ws, size_t ws_size,
                              hipStream_t stream) {
    const float* query = (const float*)d_in[0];
    const float* keys  = (const float*)d_in[1];
    const float* Wa_w  = (const float*)d_in[2];
    const float* Wa_b  = (const float*)d_in[3];
    const float* Ua_w  = (const float*)d_in[4];
    const float* Ua_b  = (const float*)d_in[5];
    const float* Va_w  = (const float*)d_in[6];
    // Va_b (d_in[7]) unused: softmax is shift-invariant, scores not an output.

    float* out     = (float*)d_out;
    float* ctx     = out;              // [32,1,1024]
    float* weights = out + B_ * H_;    // [32,2048]

    char* ws = (char*)d_ws;
    unsigned short* uab   = (unsigned short*)ws;                         // 2 MB
    float*          qsum  = (float*)(ws + 2u * 1024 * 1024);             // 128 KB
    float*          scores= (float*)(ws + 2u * 1024 * 1024 + 128 * 1024);// 256 KB

    k_zero2  <<<(B_ * H_ + B_ * S_ + 255) / 256, 256, 0, stream>>>(ctx, B_ * H_, scores, B_ * S_);
    k_cvt_ua <<<(H_ * H_) / 1024, 256, 0, stream>>>(Ua_w, uab);
    k_qproj  <<<B_ * 4, 256, 0, stream>>>(query, Wa_w, Wa_b, Ua_b, qsum);
    k_scores <<<4096, 256, 0, stream>>>(keys, uab, qsum, Va_w, scores);
    k_softmax<<<B_, 256, 0, stream>>>(scores, weights);
    k_context<<<B_ * 16 * 2, 256, 0, stream>>>(keys, weights, ctx);
}

// Round 2
// 627.683 us; speedup vs baseline: 1.0141x; 1.0141x over previous
//
#include <hip/hip_runtime.h>
#include <hip/hip_bf16.h>
#include <stdint.h>

#define B_ 32
#define S_ 2048
#define H_ 1024

typedef __attribute__((ext_vector_type(8))) short short8;
typedef __attribute__((ext_vector_type(4))) float floatx4;

__device__ inline unsigned short f32_bf16(float f) {
    union { float f; unsigned u; } v; v.f = f;
    unsigned u = v.u;
    u += 0x7fff + ((u >> 16) & 1);   // round-to-nearest-even
    return (unsigned short)(u >> 16);
}
__device__ inline unsigned pack_bf2(float a, float b) {
    return (unsigned)f32_bf16(a) | ((unsigned)f32_bf16(b) << 16);
}
__device__ inline float bf_lo(unsigned u) { union { unsigned u; float f; } v; v.u = u << 16; return v.f; }
__device__ inline float bf_hi(unsigned u) { union { unsigned u; float f; } v; v.u = u & 0xffff0000u; return v.f; }

__device__ inline float tanh_fast(float x) {
    float e = __expf(2.0f * x);
    return 1.0f - 2.0f / (e + 1.0f);
}

__device__ inline void gld16(const void* g, void* l) {
    __builtin_amdgcn_global_load_lds(
        (const __attribute__((address_space(1))) unsigned int*)g,
        (__attribute__((address_space(3))) unsigned int*)l, 16, 0, 0);
}

// ---------------- prep: keys->bf16, Ua->bf16, zero scores --------------------
#define KCVT_BLOCKS 32768          // 64M elems / 2048 per block
#define UACVT_BLOCKS 512           // 1M elems / 2048 per block
#define ZS_BLOCKS 64               // 64K floats / 1024 per block
__global__ void k_prep(const float* __restrict__ keys, unsigned short* __restrict__ keysbf,
                       const float* __restrict__ ua, unsigned short* __restrict__ uab,
                       float* __restrict__ scores) {
    int blk = blockIdx.x, t = threadIdx.x;
    if (blk < KCVT_BLOCKS + UACVT_BLOCKS) {
        const float* src; unsigned short* dst; size_t base;
        if (blk < KCVT_BLOCKS) { src = keys; dst = keysbf; base = (size_t)blk * 2048; }
        else { src = ua; dst = uab; base = (size_t)(blk - KCVT_BLOCKS) * 2048; }
        // two coalesced float4 loads, two 8B packed stores
        float4 v0 = *(const float4*)(src + base + t * 4);
        float4 v1 = *(const float4*)(src + base + 1024 + t * 4);
        *(uint2*)(dst + base + t * 4)        = make_uint2(pack_bf2(v0.x, v0.y), pack_bf2(v0.z, v0.w));
        *(uint2*)(dst + base + 1024 + t * 4) = make_uint2(pack_bf2(v1.x, v1.y), pack_bf2(v1.z, v1.w));
    } else {
        int zb = blk - KCVT_BLOCKS - UACVT_BLOCKS;
        float4 z = {0.f, 0.f, 0.f, 0.f};
        *(float4*)(scores + zb * 1024 + t * 4) = z;
    }
}

// ---------------- qsum[b,g] = query[b]·Wa_w[g] + Wa_b[g] + Ua_b[g] -----------
// 64 blocks x 256 thr: block owns 16 g-rows, all 32 batches. Coalesced Wa reads
// (16 lanes per row), query staged in LDS per 64-col chunk.
__global__ void k_qproj(const float* __restrict__ query, const float* __restrict__ Wa_w,
                        const float* __restrict__ Wa_b, const float* __restrict__ Ua_b,
                        float* __restrict__ qsum) {
    __shared__ float qs_l[32][68];
    int g0 = blockIdx.x * 16;
    int t = threadIdx.x;
    int r = t >> 4;            // local g row 0..15
    int l = t & 15;            // lane within row
    int g = g0 + r;
    float acc[32];
#pragma unroll
    for (int b = 0; b < 32; ++b) acc[b] = 0.0f;

    int sb = t >> 3;           // staging batch 0..31
    int sc = (t & 7) * 8;      // staging col 0..56
    for (int hc = 0; hc < 16; ++hc) {
        __syncthreads();
        float4 v0 = *(const float4*)(query + (size_t)sb * H_ + hc * 64 + sc);
        float4 v1 = *(const float4*)(query + (size_t)sb * H_ + hc * 64 + sc + 4);
        *(float4*)&qs_l[sb][sc]     = v0;
        *(float4*)&qs_l[sb][sc + 4] = v1;
        __syncthreads();
        float4 w = *(const float4*)(Wa_w + (size_t)g * H_ + hc * 64 + l * 4);
#pragma unroll
        for (int b = 0; b < 32; ++b) {
            float4 q4 = *(const float4*)&qs_l[b][l * 4];
            acc[b] += w.x * q4.x + w.y * q4.y + w.z * q4.z + w.w * q4.w;
        }
    }
    // reduce over 16 lanes (stays inside 16-lane groups)
#pragma unroll
    for (int b = 0; b < 32; ++b) {
        float a = acc[b];
        a += __shfl_xor(a, 1); a += __shfl_xor(a, 2);
        a += __shfl_xor(a, 4); a += __shfl_xor(a, 8);
        acc[b] = a;
    }
    if (l == 0) {
        float bias = Wa_b[g] + Ua_b[g];
#pragma unroll
        for (int b = 0; b < 32; ++b) qsum[b * H_ + g] = acc[b] + bias;
    }
}

// ---------------- fused GEMM + tanh + Va reduction ---------------------------
// C[ms,g] = sum_h keysbf[ms,h] * uab[g,h]  (NT, bf16 MFMA 16x16x32)
// scores[ms] += sum_g Va[g] * tanh(qsum[b,g] + C[ms,g])
#define BM 128
#define BN 128
#define BK 32

__global__ __launch_bounds__(256, 3) void k_scores(
    const unsigned short* __restrict__ keysbf, const unsigned short* __restrict__ uab,
    const float* __restrict__ qsum, const float* __restrict__ va,
    float* __restrict__ scores)
{
    __shared__ unsigned short Al[BM * BK];   // 8 KB, row-major [128][32]
    __shared__ unsigned short Bl[BN * BK];   // 8 KB

    int bx = blockIdx.x;
    int x  = bx & 7;                   // XCD
    int i  = bx >> 3;
    int tile_m = x * 64 + (i >> 3);
    int nc     = i & 7;
    int m_base = tile_m * BM;
    int b      = m_base >> 11;
    int g0     = nc * BN;

    int tid = threadIdx.x;
    int wid = tid >> 6, lane = tid & 63;
    int wm = wid >> 1, wn = wid & 1;
    int q = lane >> 4, cn = lane & 15;

    // ---- staging addressing (global_load_lds: wave-uniform LDS base + lane*16)
    // call j: rows w*32+j*16 .. +15; lane i -> row_local i>>2, phys col-group i&3
    // fetched global col-group = cg ^ ((row>>1)&3)   (bank-conflict swizzle)
    int rl = lane >> 2, cg = lane & 3;
    int rA0 = wid * 32 + rl,      rA1 = wid * 32 + 16 + rl;
    int gA0 = cg ^ ((rA0 >> 1) & 3), gA1 = cg ^ ((rA1 >> 1) & 3);
    const unsigned short* pA0 = keysbf + (size_t)(m_base + rA0) * H_ + gA0 * 8;
    const unsigned short* pA1 = keysbf + (size_t)(m_base + rA1) * H_ + gA1 * 8;
    const unsigned short* pB0 = uab + (size_t)(g0 + rA0) * H_ + gA0 * 8;
    const unsigned short* pB1 = uab + (size_t)(g0 + rA1) * H_ + gA1 * 8;
    unsigned short* lA0 = &Al[(wid * 32) * BK];
    unsigned short* lA1 = &Al[(wid * 32 + 16) * BK];
    unsigned short* lB0 = &Bl[(wid * 32) * BK];
    unsigned short* lB1 = &Bl[(wid * 32 + 16) * BK];

    // ---- fragment read offsets (swizzled), constant over K
    int aoff[4], boff[4];
#pragma unroll
    for (int ii = 0; ii < 4; ++ii) {
        int r = wm * 64 + ii * 16 + cn;
        aoff[ii] = r * BK + (q ^ ((r >> 1) & 3)) * 8;
        int rb = wn * 64 + ii * 16 + cn;
        boff[ii] = rb * BK + (q ^ ((rb >> 1) & 3)) * 8;
    }

    floatx4 acc[4][4];
#pragma unroll
    for (int ii = 0; ii < 4; ++ii)
#pragma unroll
        for (int jj = 0; jj < 4; ++jj)
            acc[ii][jj] = (floatx4)(0.0f);

    for (int kc = 0; kc < H_ / BK; ++kc) {
        __syncthreads();
        int ko = kc * BK;
        gld16(pA0 + ko, lA0);
        gld16(pA1 + ko, lA1);
        gld16(pB0 + ko, lB0);
        gld16(pB1 + ko, lB1);
        __syncthreads();
        short8 af[4], bf[4];
#pragma unroll
        for (int ii = 0; ii < 4; ++ii) af[ii] = *(const short8*)&Al[aoff[ii]];
#pragma unroll
        for (int jj = 0; jj < 4; ++jj) bf[jj] = *(const short8*)&Bl[boff[jj]];
#pragma unroll
        for (int ii = 0; ii < 4; ++ii)
#pragma unroll
            for (int jj = 0; jj < 4; ++jj)
                acc[ii][jj] = __builtin_amdgcn_mfma_f32_16x16x32_bf16(
                    af[ii], bf[jj], acc[ii][jj], 0, 0, 0);
    }

    // epilogue: scores partial = sum_g Va[g] * tanh(qsum[b,g] + C)
    float qs[4], vw[4];
#pragma unroll
    for (int jj = 0; jj < 4; ++jj) {
        int g = g0 + wn * 64 + jj * 16 + cn;
        qs[jj] = qsum[b * H_ + g];
        vw[jj] = va[g];
    }
#pragma unroll
    for (int ii = 0; ii < 4; ++ii) {
        float rs[4] = {0.f, 0.f, 0.f, 0.f};
#pragma unroll
        for (int jj = 0; jj < 4; ++jj) {
#pragma unroll
            for (int r = 0; r < 4; ++r)
                rs[r] += vw[jj] * tanh_fast(qs[jj] + acc[ii][jj][r]);
        }
#pragma unroll
        for (int r = 0; r < 4; ++r) {
            for (int mm = 1; mm < 16; mm <<= 1)
                rs[r] += __shfl_xor(rs[r], mm);
        }
        if (cn == 0) {
            int msrow = m_base + wm * 64 + ii * 16 + q * 4;
            float* sp = scores + b * S_ + (msrow & (S_ - 1));
            atomicAdd(sp + 0, rs[0]);
            atomicAdd(sp + 1, rs[1]);
            atomicAdd(sp + 2, rs[2]);
            atomicAdd(sp + 3, rs[3]);
        }
    }
}

// ---------------- softmax over S per batch -----------------------------------
__global__ void k_softmax(const float* __restrict__ scores, float* __restrict__ weights) {
    int b = blockIdx.x;
    int t = threadIdx.x;
    __shared__ float red[4];
    float v[8];
    float mx = -1e30f;
#pragma unroll
    for (int k = 0; k < 8; ++k) { v[k] = scores[b * S_ + t + k * 256]; mx = fmaxf(mx, v[k]); }
    for (int mm = 1; mm < 64; mm <<= 1) mx = fmaxf(mx, __shfl_xor(mx, mm));
    if ((t & 63) == 0) red[t >> 6] = mx;
    __syncthreads();
    mx = fmaxf(fmaxf(red[0], red[1]), fmaxf(red[2], red[3]));
    float sum = 0.0f;
#pragma unroll
    for (int k = 0; k < 8; ++k) { v[k] = __expf(v[k] - mx); sum += v[k]; }
    for (int mm = 1; mm < 64; mm <<= 1) sum += __shfl_xor(sum, mm);
    __syncthreads();
    if ((t & 63) == 0) red[t >> 6] = sum;
    __syncthreads();
    sum = red[0] + red[1] + red[2] + red[3];
    float inv = 1.0f / sum;
#pragma unroll
    for (int k = 0; k < 8; ++k) weights[b * S_ + t + k * 256] = v[k] * inv;
}

// ---------------- context stage 1: partial[b*64+sc*2+rp][h] ------------------
__global__ void k_ctx1(const unsigned short* __restrict__ keysbf,
                       const float* __restrict__ weights, float* __restrict__ partial) {
    int blk = blockIdx.x;          // 32 b x 32 s-chunks (64 rows each)
    int b = blk >> 5, sc = blk & 31;
    int t = threadIdx.x;
    __shared__ float wl[64];
    if (t < 64) wl[t] = weights[b * S_ + sc * 64 + t];
    __syncthreads();
    const uint4* kp = (const uint4*)(keysbf + (size_t)(b * S_ + sc * 64) * H_);
    int col = t & 127;             // uint4 col (8 bf16)
    int rp  = t >> 7;              // row parity 0/1
    float a0=0,a1=0,a2=0,a3=0,a4=0,a5=0,a6=0,a7=0;
#pragma unroll 8
    for (int s = rp; s < 64; s += 2) {
        uint4 v = kp[(size_t)s * 128 + col];
        float w = wl[s];
        a0 += w * bf_lo(v.x); a1 += w * bf_hi(v.x);
        a2 += w * bf_lo(v.y); a3 += w * bf_hi(v.y);
        a4 += w * bf_lo(v.z); a5 += w * bf_hi(v.z);
        a6 += w * bf_lo(v.w); a7 += w * bf_hi(v.w);
    }
    float* pp = partial + (size_t)(b * 64 + sc * 2 + rp) * H_ + col * 8;
    float4 o0 = {a0, a1, a2, a3}, o1 = {a4, a5, a6, a7};
    *(float4*)pp = o0;
    *(float4*)(pp + 4) = o1;
}

// ---------------- context stage 2: reduce 64 partials ------------------------
__global__ void k_ctx2(const float* __restrict__ partial, float* __restrict__ ctx) {
    int b = blockIdx.x;
    int t = threadIdx.x;
    float4 a = {0.f, 0.f, 0.f, 0.f};
#pragma unroll 8
    for (int j = 0; j < 64; ++j) {
        float4 p = *(const float4*)(partial + (size_t)(b * 64 + j) * H_ + t * 4);
        a.x += p.x; a.y += p.y; a.z += p.z; a.w += p.w;
    }
    *(float4*)(ctx + b * H_ + t * 4) = a;
}

// -----------------------------------------------------------------------------
extern "C" void kernel_launch(void* const* d_in, const int* in_sizes, int n_in,
                              void* d_out, int out_size, void* d_ws, size_t ws_size,
                              hipStream_t stream) {
    const float* query = (const float*)d_in[0];
    const float* keys  = (const float*)d_in[1];
    const float* Wa_w  = (const float*)d_in[2];
    const float* Wa_b  = (const float*)d_in[3];
    const float* Ua_w  = (const float*)d_in[4];
    const float* Ua_b  = (const float*)d_in[5];
    const float* Va_w  = (const float*)d_in[6];
    // Va_b unused: softmax shift-invariant, scores not an output.

    float* out     = (float*)d_out;
    float* ctx     = out;              // [32,1,1024]
    float* weights = out + B_ * H_;    // [32,2048]

    char* ws = (char*)d_ws;
    unsigned short* keysbf = (unsigned short*)ws;                          // 128 MB
    unsigned short* uab    = (unsigned short*)(ws + 134217728);            // 2 MB
    float*          qsum   = (float*)(ws + 134217728 + 2097152);           // 128 KB
    float*          scores = (float*)(ws + 134217728 + 2097152 + 131072);  // 256 KB
    float*          partial= (float*)(ws + 134217728 + 2097152 + 131072 + 262144); // 8 MB

    k_prep   <<<KCVT_BLOCKS + UACVT_BLOCKS + ZS_BLOCKS, 256, 0, stream>>>(keys, keysbf, Ua_w, uab, scores);
    k_qproj  <<<64, 256, 0, stream>>>(query, Wa_w, Wa_b, Ua_b, qsum);
    k_scores <<<4096, 256, 0, stream>>>(keysbf, uab, qsum, Va_w, scores);
    k_softmax<<<B_, 256, 0, stream>>>(scores, weights);
    k_ctx1   <<<B_ * 32, 256, 0, stream>>>(keysbf, weights, partial);
    k_ctx2   <<<B_, 256, 0, stream>>>(partial, ctx);
}

// Round 3
// 600.164 us; speedup vs baseline: 1.0606x; 1.0459x over previous
//
#include <hip/hip_runtime.h>
#include <hip/hip_bf16.h>
#include <stdint.h>

#define B_ 32
#define S_ 2048
#define H_ 1024

typedef __attribute__((ext_vector_type(8))) short short8;
typedef __attribute__((ext_vector_type(4))) float floatx4;

__device__ inline unsigned short f32_bf16(float f) {
    union { float f; unsigned u; } v; v.f = f;
    unsigned u = v.u;
    u += 0x7fff + ((u >> 16) & 1);   // round-to-nearest-even
    return (unsigned short)(u >> 16);
}
__device__ inline unsigned pack_bf2(float a, float b) {
    return (unsigned)f32_bf16(a) | ((unsigned)f32_bf16(b) << 16);
}
__device__ inline float bf_lo(unsigned u) { union { unsigned u; float f; } v; v.u = u << 16; return v.f; }
__device__ inline float bf_hi(unsigned u) { union { unsigned u; float f; } v; v.u = u & 0xffff0000u; return v.f; }

__device__ inline float tanh_fast(float x) {
    float e = __expf(2.0f * x);
    return 1.0f - 2.0f / (e + 1.0f);
}

__device__ inline void gld16(const void* g, void* l) {
    __builtin_amdgcn_global_load_lds(
        (const __attribute__((address_space(1))) unsigned int*)g,
        (__attribute__((address_space(3))) unsigned int*)l, 16, 0, 0);
}

// ---------------- prep: keys->bf16, Ua->bf16, zero scores, qproj -------------
#define KCVT_BLOCKS 32768          // 64M elems / 2048 per block
#define UACVT_BLOCKS 512           // 1M elems / 2048 per block
#define ZS_BLOCKS 64               // 64K floats / 1024 per block
#define QP_BLOCKS 64
__global__ void k_prep(const float* __restrict__ keys, unsigned short* __restrict__ keysbf,
                       const float* __restrict__ ua, unsigned short* __restrict__ uab,
                       float* __restrict__ scores,
                       const float* __restrict__ query, const float* __restrict__ Wa_w,
                       const float* __restrict__ Wa_b, const float* __restrict__ Ua_b,
                       float* __restrict__ qsum) {
    int blk = blockIdx.x, t = threadIdx.x;
    if (blk < KCVT_BLOCKS + UACVT_BLOCKS) {
        const float* src; unsigned short* dst; size_t base;
        if (blk < KCVT_BLOCKS) { src = keys; dst = keysbf; base = (size_t)blk * 2048; }
        else { src = ua; dst = uab; base = (size_t)(blk - KCVT_BLOCKS) * 2048; }
        float4 v0 = *(const float4*)(src + base + t * 4);
        float4 v1 = *(const float4*)(src + base + 1024 + t * 4);
        *(uint2*)(dst + base + t * 4)        = make_uint2(pack_bf2(v0.x, v0.y), pack_bf2(v0.z, v0.w));
        *(uint2*)(dst + base + 1024 + t * 4) = make_uint2(pack_bf2(v1.x, v1.y), pack_bf2(v1.z, v1.w));
    } else if (blk < KCVT_BLOCKS + UACVT_BLOCKS + ZS_BLOCKS) {
        int zb = blk - KCVT_BLOCKS - UACVT_BLOCKS;
        float4 z = {0.f, 0.f, 0.f, 0.f};
        *(float4*)(scores + zb * 1024 + t * 4) = z;
    } else {
        // qproj: qsum[b,g] = query[b]·Wa_w[g] + Wa_b[g] + Ua_b[g]
        __shared__ float qs_l[32][68];
        int g0 = (blk - KCVT_BLOCKS - UACVT_BLOCKS - ZS_BLOCKS) * 16;
        int r = t >> 4, l = t & 15;
        int g = g0 + r;
        float acc[32];
#pragma unroll
        for (int b = 0; b < 32; ++b) acc[b] = 0.0f;
        int sb = t >> 3, sc = (t & 7) * 8;
        for (int hc = 0; hc < 16; ++hc) {
            __syncthreads();
            float4 v0 = *(const float4*)(query + (size_t)sb * H_ + hc * 64 + sc);
            float4 v1 = *(const float4*)(query + (size_t)sb * H_ + hc * 64 + sc + 4);
            *(float4*)&qs_l[sb][sc]     = v0;
            *(float4*)&qs_l[sb][sc + 4] = v1;
            __syncthreads();
            float4 w = *(const float4*)(Wa_w + (size_t)g * H_ + hc * 64 + l * 4);
#pragma unroll
            for (int b = 0; b < 32; ++b) {
                float4 q4 = *(const float4*)&qs_l[b][l * 4];
                acc[b] += w.x * q4.x + w.y * q4.y + w.z * q4.z + w.w * q4.w;
            }
        }
#pragma unroll
        for (int b = 0; b < 32; ++b) {
            float a = acc[b];
            a += __shfl_xor(a, 1); a += __shfl_xor(a, 2);
            a += __shfl_xor(a, 4); a += __shfl_xor(a, 8);
            acc[b] = a;
        }
        if (l == 0) {
            float bias = Wa_b[g] + Ua_b[g];
#pragma unroll
            for (int b = 0; b < 32; ++b) qsum[b * H_ + g] = acc[b] + bias;
        }
    }
}

// ---------------- fused GEMM + tanh + Va reduction ---------------------------
// C[ms,g] = sum_h keysbf[ms,h] * uab[g,h]  (NT, bf16 MFMA 16x16x32), BK=64
// scores[ms] += sum_g Va[g] * tanh(qsum[b,g] + C[ms,g])
#define BM 128
#define BN 128
#define BK 64

__global__ __launch_bounds__(256, 3) void k_scores(
    const unsigned short* __restrict__ keysbf, const unsigned short* __restrict__ uab,
    const float* __restrict__ qsum, const float* __restrict__ va,
    float* __restrict__ scores)
{
    __shared__ unsigned short Al[BM * BK];   // 16 KB, row-major [128][64], col-group swizzled
    __shared__ unsigned short Bl[BN * BK];   // 16 KB

    int bx = blockIdx.x;
    int x  = bx & 7;                   // XCD
    int i  = bx >> 3;
    int tile_m = x * 64 + (i >> 3);
    int nc     = i & 7;
    int m_base = tile_m * BM;
    int b      = m_base >> 11;
    int g0     = nc * BN;

    int tid = threadIdx.x;
    int wid = tid >> 6, lane = tid & 63;
    int wm = wid >> 1, wn = wid & 1;
    int q = lane >> 4, cn = lane & 15;

    // ---- staging (global_load_lds, 16B/lane): call j stages 8 rows x 8 col-groups.
    // phys col-group (lane&7) holds global col-group (lane&7)^(row&7); row&7 == lane>>3.
    int rl8 = lane >> 3;               // row within call, also row&7
    int gcg = (lane & 7) ^ rl8;        // fetched global col-group
    const unsigned short* pA[4];
    const unsigned short* pB[4];
    unsigned short* lA[4];
    unsigned short* lB[4];
#pragma unroll
    for (int j = 0; j < 4; ++j) {
        int row = wid * 32 + j * 8 + rl8;
        pA[j] = keysbf + (size_t)(m_base + row) * H_ + gcg * 8;
        pB[j] = uab    + (size_t)(g0     + row) * H_ + gcg * 8;
        lA[j] = &Al[(wid * 32 + j * 8) * BK];
        lB[j] = &Bl[(wid * 32 + j * 8) * BK];
    }

    // ---- fragment read offsets: row r, k-chunk kk (0/1), col = kk*32+q*8
    // phys col-group = (kk*4+q) ^ (r&7); r&7 == cn&7 for our rows.
    int aoff[2][4], boff[2][4];
#pragma unroll
    for (int kk = 0; kk < 2; ++kk)
#pragma unroll
        for (int ii = 0; ii < 4; ++ii) {
            int r  = wm * 64 + ii * 16 + cn;
            aoff[kk][ii] = r * BK + ((kk * 4 + q) ^ (r & 7)) * 8;
            int rb = wn * 64 + ii * 16 + cn;
            boff[kk][ii] = rb * BK + ((kk * 4 + q) ^ (rb & 7)) * 8;
        }

    floatx4 acc[4][4];
#pragma unroll
    for (int ii = 0; ii < 4; ++ii)
#pragma unroll
        for (int jj = 0; jj < 4; ++jj)
            acc[ii][jj] = (floatx4)(0.0f);

    for (int kc = 0; kc < H_ / BK; ++kc) {
        __syncthreads();
        int ko = kc * BK;
#pragma unroll
        for (int j = 0; j < 4; ++j) {
            gld16(pA[j] + ko, lA[j]);
            gld16(pB[j] + ko, lB[j]);
        }
        __syncthreads();
#pragma unroll
        for (int kk = 0; kk < 2; ++kk) {
            short8 af[4], bf[4];
#pragma unroll
            for (int ii = 0; ii < 4; ++ii) af[ii] = *(const short8*)&Al[aoff[kk][ii]];
#pragma unroll
            for (int jj = 0; jj < 4; ++jj) bf[jj] = *(const short8*)&Bl[boff[kk][jj]];
#pragma unroll
            for (int ii = 0; ii < 4; ++ii)
#pragma unroll
                for (int jj = 0; jj < 4; ++jj)
                    acc[ii][jj] = __builtin_amdgcn_mfma_f32_16x16x32_bf16(
                        af[ii], bf[jj], acc[ii][jj], 0, 0, 0);
        }
    }

    // epilogue: scores partial = sum_g Va[g] * tanh(qsum[b,g] + C)
    float qs[4], vw[4];
#pragma unroll
    for (int jj = 0; jj < 4; ++jj) {
        int g = g0 + wn * 64 + jj * 16 + cn;
        qs[jj] = qsum[b * H_ + g];
        vw[jj] = va[g];
    }
#pragma unroll
    for (int ii = 0; ii < 4; ++ii) {
        float rs[4] = {0.f, 0.f, 0.f, 0.f};
#pragma unroll
        for (int jj = 0; jj < 4; ++jj) {
#pragma unroll
            for (int r = 0; r < 4; ++r)
                rs[r] += vw[jj] * tanh_fast(qs[jj] + acc[ii][jj][r]);
        }
#pragma unroll
        for (int r = 0; r < 4; ++r) {
            for (int mm = 1; mm < 16; mm <<= 1)
                rs[r] += __shfl_xor(rs[r], mm);
        }
        if (cn == 0) {
            int msrow = m_base + wm * 64 + ii * 16 + q * 4;
            float* sp = scores + b * S_ + (msrow & (S_ - 1));
            atomicAdd(sp + 0, rs[0]);
            atomicAdd(sp + 1, rs[1]);
            atomicAdd(sp + 2, rs[2]);
            atomicAdd(sp + 3, rs[3]);
        }
    }
}

// ---------------- softmax over S per batch -----------------------------------
__global__ void k_softmax(const float* __restrict__ scores, float* __restrict__ weights) {
    int b = blockIdx.x;
    int t = threadIdx.x;
    __shared__ float red[4];
    float v[8];
    float mx = -1e30f;
#pragma unroll
    for (int k = 0; k < 8; ++k) { v[k] = scores[b * S_ + t + k * 256]; mx = fmaxf(mx, v[k]); }
    for (int mm = 1; mm < 64; mm <<= 1) mx = fmaxf(mx, __shfl_xor(mx, mm));
    if ((t & 63) == 0) red[t >> 6] = mx;
    __syncthreads();
    mx = fmaxf(fmaxf(red[0], red[1]), fmaxf(red[2], red[3]));
    float sum = 0.0f;
#pragma unroll
    for (int k = 0; k < 8; ++k) { v[k] = __expf(v[k] - mx); sum += v[k]; }
    for (int mm = 1; mm < 64; mm <<= 1) sum += __shfl_xor(sum, mm);
    __syncthreads();
    if ((t & 63) == 0) red[t >> 6] = sum;
    __syncthreads();
    sum = red[0] + red[1] + red[2] + red[3];
    float inv = 1.0f / sum;
#pragma unroll
    for (int k = 0; k < 8; ++k) weights[b * S_ + t + k * 256] = v[k] * inv;
}

// ---------------- context stage 1: partial[b*64+sc*2+rp][h] ------------------
__global__ void k_ctx1(const unsigned short* __restrict__ keysbf,
                       const float* __restrict__ weights, float* __restrict__ partial) {
    int blk = blockIdx.x;          // 32 b x 32 s-chunks (64 rows each)
    int b = blk >> 5, sc = blk & 31;
    int t = threadIdx.x;
    __shared__ float wl[64];
    if (t < 64) wl[t] = weights[b * S_ + sc * 64 + t];
    __syncthreads();
    const uint4* kp = (const uint4*)(keysbf + (size_t)(b * S_ + sc * 64) * H_);
    int col = t & 127;             // uint4 col (8 bf16)
    int rp  = t >> 7;              // row parity 0/1
    float a0=0,a1=0,a2=0,a3=0,a4=0,a5=0,a6=0,a7=0;
#pragma unroll 8
    for (int s = rp; s < 64; s += 2) {
        uint4 v = kp[(size_t)s * 128 + col];
        float w = wl[s];
        a0 += w * bf_lo(v.x); a1 += w * bf_hi(v.x);
        a2 += w * bf_lo(v.y); a3 += w * bf_hi(v.y);
        a4 += w * bf_lo(v.z); a5 += w * bf_hi(v.z);
        a6 += w * bf_lo(v.w); a7 += w * bf_hi(v.w);
    }
    float* pp = partial + (size_t)(b * 64 + sc * 2 + rp) * H_ + col * 8;
    float4 o0 = {a0, a1, a2, a3}, o1 = {a4, a5, a6, a7};
    *(float4*)pp = o0;
    *(float4*)(pp + 4) = o1;
}

// ---------------- context stage 2: reduce 64 partials ------------------------
__global__ void k_ctx2(const float* __restrict__ partial, float* __restrict__ ctx) {
    int b = blockIdx.x;
    int t = threadIdx.x;
    float4 a = {0.f, 0.f, 0.f, 0.f};
#pragma unroll 8
    for (int j = 0; j < 64; ++j) {
        float4 p = *(const float4*)(partial + (size_t)(b * 64 + j) * H_ + t * 4);
        a.x += p.x; a.y += p.y; a.z += p.z; a.w += p.w;
    }
    *(float4*)(ctx + b * H_ + t * 4) = a;
}

// -----------------------------------------------------------------------------
extern "C" void kernel_launch(void* const* d_in, const int* in_sizes, int n_in,
                              void* d_out, int out_size, void* d_ws, size_t ws_size,
                              hipStream_t stream) {
    const float* query = (const float*)d_in[0];
    const float* keys  = (const float*)d_in[1];
    const float* Wa_w  = (const float*)d_in[2];
    const float* Wa_b  = (const float*)d_in[3];
    const float* Ua_w  = (const float*)d_in[4];
    const float* Ua_b  = (const float*)d_in[5];
    const float* Va_w  = (const float*)d_in[6];
    // Va_b unused: softmax shift-invariant, scores not an output.

    float* out     = (float*)d_out;
    float* ctx     = out;              // [32,1,1024]
    float* weights = out + B_ * H_;    // [32,2048]

    char* ws = (char*)d_ws;
    unsigned short* keysbf = (unsigned short*)ws;                          // 128 MB
    unsigned short* uab    = (unsigned short*)(ws + 134217728);            // 2 MB
    float*          qsum   = (float*)(ws + 134217728 + 2097152);           // 128 KB
    float*          scores = (float*)(ws + 134217728 + 2097152 + 131072);  // 256 KB
    float*          partial= (float*)(ws + 134217728 + 2097152 + 131072 + 262144); // 8 MB

    k_prep   <<<KCVT_BLOCKS + UACVT_BLOCKS + ZS_BLOCKS + QP_BLOCKS, 256, 0, stream>>>(
        keys, keysbf, Ua_w, uab, scores, query, Wa_w, Wa_b, Ua_b, qsum);
    k_scores <<<4096, 256, 0, stream>>>(keysbf, uab, qsum, Va_w, scores);
    k_softmax<<<B_, 256, 0, stream>>>(scores, weights);
    k_ctx1   <<<B_ * 32, 256, 0, stream>>>(keysbf, weights, partial);
    k_ctx2   <<<B_, 256, 0, stream>>>(partial, ctx);
}

// Round 4
// 592.340 us; speedup vs baseline: 1.0746x; 1.0132x over previous
//
#include <hip/hip_runtime.h>
#include <hip/hip_bf16.h>
#include <stdint.h>

#define B_ 32
#define S_ 2048
#define H_ 1024

typedef __attribute__((ext_vector_type(8))) short short8;
typedef __attribute__((ext_vector_type(4))) float floatx4;

__device__ inline unsigned short f32_bf16(float f) {
    union { float f; unsigned u; } v; v.f = f;
    unsigned u = v.u;
    u += 0x7fff + ((u >> 16) & 1);   // round-to-nearest-even
    return (unsigned short)(u >> 16);
}
__device__ inline unsigned pack_bf2(float a, float b) {
    return (unsigned)f32_bf16(a) | ((unsigned)f32_bf16(b) << 16);
}
__device__ inline float bf_lo(unsigned u) { union { unsigned u; float f; } v; v.u = u << 16; return v.f; }
__device__ inline float bf_hi(unsigned u) { union { unsigned u; float f; } v; v.u = u & 0xffff0000u; return v.f; }

__device__ inline float tanh_fast(float x) {
    float e = __expf(2.0f * x);
    return 1.0f - 2.0f / (e + 1.0f);
}

__device__ inline void gld16(const void* g, void* l) {
    __builtin_amdgcn_global_load_lds(
        (const __attribute__((address_space(1))) unsigned int*)g,
        (__attribute__((address_space(3))) unsigned int*)l, 16, 0, 0);
}

// ---------------- prep: keys->bf16, Ua->bf16, qproj --------------------------
#define KCVT_BLOCKS 32768          // 64M elems / 2048 per block
#define UACVT_BLOCKS 512           // 1M elems / 2048 per block
#define QP_BLOCKS 64
__global__ void k_prep(const float* __restrict__ keys, unsigned short* __restrict__ keysbf,
                       const float* __restrict__ ua, unsigned short* __restrict__ uab,
                       const float* __restrict__ query, const float* __restrict__ Wa_w,
                       const float* __restrict__ Wa_b, const float* __restrict__ Ua_b,
                       float* __restrict__ qsum) {
    int blk = blockIdx.x, t = threadIdx.x;
    if (blk < KCVT_BLOCKS + UACVT_BLOCKS) {
        const float* src; unsigned short* dst; size_t base;
        if (blk < KCVT_BLOCKS) { src = keys; dst = keysbf; base = (size_t)blk * 2048; }
        else { src = ua; dst = uab; base = (size_t)(blk - KCVT_BLOCKS) * 2048; }
        float4 v0 = *(const float4*)(src + base + t * 4);
        float4 v1 = *(const float4*)(src + base + 1024 + t * 4);
        *(uint2*)(dst + base + t * 4)        = make_uint2(pack_bf2(v0.x, v0.y), pack_bf2(v0.z, v0.w));
        *(uint2*)(dst + base + 1024 + t * 4) = make_uint2(pack_bf2(v1.x, v1.y), pack_bf2(v1.z, v1.w));
    } else {
        // qproj: qsum[b,g] = query[b]·Wa_w[g] + Wa_b[g] + Ua_b[g]
        __shared__ float qs_l[32][68];
        int g0 = (blk - KCVT_BLOCKS - UACVT_BLOCKS) * 16;
        int r = t >> 4, l = t & 15;
        int g = g0 + r;
        float acc[32];
#pragma unroll
        for (int b = 0; b < 32; ++b) acc[b] = 0.0f;
        int sb = t >> 3, sc = (t & 7) * 8;
        for (int hc = 0; hc < 16; ++hc) {
            __syncthreads();
            float4 v0 = *(const float4*)(query + (size_t)sb * H_ + hc * 64 + sc);
            float4 v1 = *(const float4*)(query + (size_t)sb * H_ + hc * 64 + sc + 4);
            *(float4*)&qs_l[sb][sc]     = v0;
            *(float4*)&qs_l[sb][sc + 4] = v1;
            __syncthreads();
            float4 w = *(const float4*)(Wa_w + (size_t)g * H_ + hc * 64 + l * 4);
#pragma unroll
            for (int b = 0; b < 32; ++b) {
                float4 q4 = *(const float4*)&qs_l[b][l * 4];
                acc[b] += w.x * q4.x + w.y * q4.y + w.z * q4.z + w.w * q4.w;
            }
        }
#pragma unroll
        for (int b = 0; b < 32; ++b) {
            float a = acc[b];
            a += __shfl_xor(a, 1); a += __shfl_xor(a, 2);
            a += __shfl_xor(a, 4); a += __shfl_xor(a, 8);
            acc[b] = a;
        }
        if (l == 0) {
            float bias = Wa_b[g] + Ua_b[g];
#pragma unroll
            for (int b = 0; b < 32; ++b) qsum[b * H_ + g] = acc[b] + bias;
        }
    }
}

// ---------------- fused GEMM + tanh + Va reduction ---------------------------
// C[ms,g] = sum_h keysbf[ms,h] * uab[g,h]  (NT, bf16 MFMA 16x16x32), BK=64
// scores_p[nc][ms] = sum_{g in chunk nc} Va[g] * tanh(qsum[b,g] + C[ms,g])
#define BM 128
#define BN 128
#define BK 64

__global__ __launch_bounds__(256, 4) void k_scores(
    const unsigned short* __restrict__ keysbf, const unsigned short* __restrict__ uab,
    const float* __restrict__ qsum, const float* __restrict__ va,
    float* __restrict__ scores_p)
{
    __shared__ unsigned short Al[BM * BK];   // 16 KB, row-major [128][64], col-group swizzled
    __shared__ unsigned short Bl[BN * BK];   // 16 KB

    int bx = blockIdx.x;
    int x  = bx & 7;                   // XCD
    int i  = bx >> 3;
    int tile_m = x * 64 + (i >> 3);
    int nc     = i & 7;
    int m_base = tile_m * BM;
    int b      = m_base >> 11;
    int g0     = nc * BN;

    int tid = threadIdx.x;
    int wid = tid >> 6, lane = tid & 63;
    int wm = wid >> 1, wn = wid & 1;
    int q = lane >> 4, cn = lane & 15;

    // ---- staging (global_load_lds, 16B/lane): call j stages 8 rows x 8 col-groups.
    // phys col-group (lane&7) holds global col-group (lane&7)^(row&7); row&7 == lane>>3.
    int rl8 = lane >> 3;               // row within call, also row&7
    int gcg = (lane & 7) ^ rl8;        // fetched global col-group
    const unsigned short* pA[4];
    const unsigned short* pB[4];
    unsigned short* lA[4];
    unsigned short* lB[4];
#pragma unroll
    for (int j = 0; j < 4; ++j) {
        int row = wid * 32 + j * 8 + rl8;
        pA[j] = keysbf + (size_t)(m_base + row) * H_ + gcg * 8;
        pB[j] = uab    + (size_t)(g0     + row) * H_ + gcg * 8;
        lA[j] = &Al[(wid * 32 + j * 8) * BK];
        lB[j] = &Bl[(wid * 32 + j * 8) * BK];
    }

    // ---- fragment read offsets: row r, k-chunk kk (0/1), col = kk*32+q*8
    int aoff[2][4], boff[2][4];
#pragma unroll
    for (int kk = 0; kk < 2; ++kk)
#pragma unroll
        for (int ii = 0; ii < 4; ++ii) {
            int r  = wm * 64 + ii * 16 + cn;
            aoff[kk][ii] = r * BK + ((kk * 4 + q) ^ (r & 7)) * 8;
            int rb = wn * 64 + ii * 16 + cn;
            boff[kk][ii] = rb * BK + ((kk * 4 + q) ^ (rb & 7)) * 8;
        }

    floatx4 acc[4][4];
#pragma unroll
    for (int ii = 0; ii < 4; ++ii)
#pragma unroll
        for (int jj = 0; jj < 4; ++jj)
            acc[ii][jj] = (floatx4)(0.0f);

    for (int kc = 0; kc < H_ / BK; ++kc) {
        __syncthreads();
        int ko = kc * BK;
#pragma unroll
        for (int j = 0; j < 4; ++j) {
            gld16(pA[j] + ko, lA[j]);
            gld16(pB[j] + ko, lB[j]);
        }
        __syncthreads();
#pragma unroll
        for (int kk = 0; kk < 2; ++kk) {
            short8 af[4], bf[4];
#pragma unroll
            for (int ii = 0; ii < 4; ++ii) af[ii] = *(const short8*)&Al[aoff[kk][ii]];
#pragma unroll
            for (int jj = 0; jj < 4; ++jj) bf[jj] = *(const short8*)&Bl[boff[kk][jj]];
#pragma unroll
            for (int ii = 0; ii < 4; ++ii)
#pragma unroll
                for (int jj = 0; jj < 4; ++jj)
                    acc[ii][jj] = __builtin_amdgcn_mfma_f32_16x16x32_bf16(
                        af[ii], bf[jj], acc[ii][jj], 0, 0, 0);
        }
    }

    // epilogue: scores_p[nc] partial = sum_g Va[g] * tanh(qsum[b,g] + C)
    float qs[4], vw[4];
#pragma unroll
    for (int jj = 0; jj < 4; ++jj) {
        int g = g0 + wn * 64 + jj * 16 + cn;
        qs[jj] = qsum[b * H_ + g];
        vw[jj] = va[g];
    }
    float* slab = scores_p + (size_t)nc * (B_ * S_) + b * S_;
#pragma unroll
    for (int ii = 0; ii < 4; ++ii) {
        float rs[4] = {0.f, 0.f, 0.f, 0.f};
#pragma unroll
        for (int jj = 0; jj < 4; ++jj) {
#pragma unroll
            for (int r = 0; r < 4; ++r)
                rs[r] += vw[jj] * tanh_fast(qs[jj] + acc[ii][jj][r]);
        }
        // reduce over the two waves' wn? no — wn handled across slabs? both wn
        // cover different g within SAME nc chunk: need cross-wn sum. wn waves
        // write disjoint slabs? They don't — same nc. Reduce wn pair via LDS-free
        // trick: both waves store to same rows -> must combine. Use shfl only
        // within wave; cross-wave combine via atomicAdd-free: let wn=0 and wn=1
        // write adjacent halves? They compute different g-halves of same rows.
        // Solution: reduce within wave, then one atomicAdd per pair (cheap: 2
        // waves only). scores_p zero not needed if wn0 stores, wn1 adds? Race.
        // Use atomicAdd on slab initialized by... simplest: keep per-wn slabs.
#pragma unroll
        for (int r = 0; r < 4; ++r) {
            for (int mm = 1; mm < 16; mm <<= 1)
                rs[r] += __shfl_xor(rs[r], mm);
        }
        if (cn == 0) {
            int msrow = (m_base & (S_ - 1)) + wm * 64 + ii * 16 + q * 4;
            float* sp = slab + (size_t)wn * (8 * B_ * S_) + msrow;
            sp[0] = rs[0]; sp[1] = rs[1]; sp[2] = rs[2]; sp[3] = rs[3];
        }
    }
}

// ---------------- softmax over S per batch (reduces 16 partial slabs) --------
__global__ void k_softmax(const float* __restrict__ scores_p, float* __restrict__ weights) {
    int b = blockIdx.x;
    int t = threadIdx.x;
    __shared__ float red[4];
    float v[8];
    float mx = -1e30f;
#pragma unroll
    for (int k = 0; k < 8; ++k) {
        int idx = b * S_ + t + k * 256;
        float s = 0.0f;
#pragma unroll
        for (int p = 0; p < 16; ++p) s += scores_p[(size_t)p * (B_ * S_) + idx];
        v[k] = s; mx = fmaxf(mx, s);
    }
    for (int mm = 1; mm < 64; mm <<= 1) mx = fmaxf(mx, __shfl_xor(mx, mm));
    if ((t & 63) == 0) red[t >> 6] = mx;
    __syncthreads();
    mx = fmaxf(fmaxf(red[0], red[1]), fmaxf(red[2], red[3]));
    float sum = 0.0f;
#pragma unroll
    for (int k = 0; k < 8; ++k) { v[k] = __expf(v[k] - mx); sum += v[k]; }
    for (int mm = 1; mm < 64; mm <<= 1) sum += __shfl_xor(sum, mm);
    __syncthreads();
    if ((t & 63) == 0) red[t >> 6] = sum;
    __syncthreads();
    sum = red[0] + red[1] + red[2] + red[3];
    float inv = 1.0f / sum;
#pragma unroll
    for (int k = 0; k < 8; ++k) weights[b * S_ + t + k * 256] = v[k] * inv;
}

// ---------------- context stage 1: partial[b*64+sc*2+rp][h] ------------------
__global__ void k_ctx1(const unsigned short* __restrict__ keysbf,
                       const float* __restrict__ weights, float* __restrict__ partial) {
    int blk = blockIdx.x;          // 32 b x 32 s-chunks (64 rows each)
    int b = blk >> 5, sc = blk & 31;
    int t = threadIdx.x;
    __shared__ float wl[64];
    if (t < 64) wl[t] = weights[b * S_ + sc * 64 + t];
    __syncthreads();
    const uint4* kp = (const uint4*)(keysbf + (size_t)(b * S_ + sc * 64) * H_);
    int col = t & 127;             // uint4 col (8 bf16)
    int rp  = t >> 7;              // row parity 0/1
    float a0=0,a1=0,a2=0,a3=0,a4=0,a5=0,a6=0,a7=0;
#pragma unroll 8
    for (int s = rp; s < 64; s += 2) {
        uint4 v = kp[(size_t)s * 128 + col];
        float w = wl[s];
        a0 += w * bf_lo(v.x); a1 += w * bf_hi(v.x);
        a2 += w * bf_lo(v.y); a3 += w * bf_hi(v.y);
        a4 += w * bf_lo(v.z); a5 += w * bf_hi(v.z);
        a6 += w * bf_lo(v.w); a7 += w * bf_hi(v.w);
    }
    float* pp = partial + (size_t)(b * 64 + sc * 2 + rp) * H_ + col * 8;
    float4 o0 = {a0, a1, a2, a3}, o1 = {a4, a5, a6, a7};
    *(float4*)pp = o0;
    *(float4*)(pp + 4) = o1;
}

// ---------------- context stage 2: reduce 64 partials ------------------------
__global__ void k_ctx2(const float* __restrict__ partial, float* __restrict__ ctx) {
    int b = blockIdx.x;
    int t = threadIdx.x;
    float4 a = {0.f, 0.f, 0.f, 0.f};
#pragma unroll 8
    for (int j = 0; j < 64; ++j) {
        float4 p = *(const float4*)(partial + (size_t)(b * 64 + j) * H_ + t * 4);
        a.x += p.x; a.y += p.y; a.z += p.z; a.w += p.w;
    }
    *(float4*)(ctx + b * H_ + t * 4) = a;
}

// -----------------------------------------------------------------------------
extern "C" void kernel_launch(void* const* d_in, const int* in_sizes, int n_in,
                              void* d_out, int out_size, void* d_ws, size_t ws_size,
                              hipStream_t stream) {
    const float* query = (const float*)d_in[0];
    const float* keys  = (const float*)d_in[1];
    const float* Wa_w  = (const float*)d_in[2];
    const float* Wa_b  = (const float*)d_in[3];
    const float* Ua_w  = (const float*)d_in[4];
    const float* Ua_b  = (const float*)d_in[5];
    const float* Va_w  = (const float*)d_in[6];
    // Va_b unused: softmax shift-invariant, scores not an output.

    float* out     = (float*)d_out;
    float* ctx     = out;              // [32,1,1024]
    float* weights = out + B_ * H_;    // [32,2048]

    char* ws = (char*)d_ws;
    unsigned short* keysbf  = (unsigned short*)ws;                          // 128 MB
    unsigned short* uab     = (unsigned short*)(ws + 134217728);            // 2 MB
    float*          qsum    = (float*)(ws + 134217728 + 2097152);           // 128 KB
    float*          scores_p= (float*)(ws + 134217728 + 2097152 + 131072);  // 16 slabs x 256 KB = 4 MB
    float*          partial = (float*)(ws + 134217728 + 2097152 + 131072 + 4194304); // 8 MB

    k_prep   <<<KCVT_BLOCKS + UACVT_BLOCKS + QP_BLOCKS, 256, 0, stream>>>(
        keys, keysbf, Ua_w, uab, query, Wa_w, Wa_b, Ua_b, qsum);
    k_scores <<<4096, 256, 0, stream>>>(keysbf, uab, qsum, Va_w, scores_p);
    k_softmax<<<B_, 256, 0, stream>>>(scores_p, weights);
    k_ctx1   <<<B_ * 32, 256, 0, stream>>>(keysbf, weights, partial);
    k_ctx2   <<<B_, 256, 0, stream>>>(partial, ctx);
}